// Round 3
// baseline (324.867 us; speedup 1.0000x reference)
//
#include <hip/hip_runtime.h>
#include <math.h>

namespace {

constexpr int NN = 20000;   // nodes
constexpr int NE = 400000;  // edges

constexpr float RS8   = 0.35355339059327373f;  // 1/sqrt(8)
constexpr float RS128 = 0.08838834764831845f;  // 1/sqrt(128)

__device__ __forceinline__ float silu_f(float x) {
    return x / (1.0f + __expf(-x));
}

// ---------------- node kernel: sc, nf, qk ----------------
__global__ __launch_bounds__(256) void node_kernel(
    const float* __restrict__ node_input, const float* __restrict__ node_attr,
    const float* __restrict__ W_sc, const float* __restrict__ W_lin1,
    const float* __restrict__ W_hq, const float* __restrict__ W_dot,
    float* __restrict__ nf_out, float* __restrict__ qk_out, float* __restrict__ sc_out)
{
    __shared__ float sWsc[2048];   // [a][b][c] (16,8,16), scale folded
    __shared__ float sW1[256];     // [a][c] (16,16)
    __shared__ float sWq[128];     // [a][c] (16,8)
    __shared__ float sdot[64];     // [a][c] (8,8)
    for (int i = threadIdx.x; i < 2048; i += 256) sWsc[i] = W_sc[i] * RS128;
    if (threadIdx.x < 256) sW1[threadIdx.x] = W_lin1[threadIdx.x] * 0.25f;
    if (threadIdx.x < 128) sWq[threadIdx.x] = W_hq[threadIdx.x] * 0.25f;
    if (threadIdx.x < 64)  sdot[threadIdx.x] = W_dot[threadIdx.x] * 0.125f;  // 1/sqrt(64)
    __syncthreads();

    int n = blockIdx.x * 256 + threadIdx.x;
    if (n >= NN) return;

    float ni[16], na[8];
    {
        const float4* p = (const float4*)(node_input + (size_t)n * 16);
        #pragma unroll
        for (int j = 0; j < 4; ++j) {
            float4 t = p[j];
            ni[4*j+0]=t.x; ni[4*j+1]=t.y; ni[4*j+2]=t.z; ni[4*j+3]=t.w;
        }
        const float4* pa = (const float4*)(node_attr + (size_t)n * 8);
        #pragma unroll
        for (int j = 0; j < 2; ++j) {
            float4 t = pa[j];
            na[4*j+0]=t.x; na[4*j+1]=t.y; na[4*j+2]=t.z; na[4*j+3]=t.w;
        }
    }

    float sc[16];
    #pragma unroll
    for (int c = 0; c < 16; ++c) sc[c] = 0.f;
    #pragma unroll 4
    for (int a = 0; a < 16; ++a) {
        #pragma unroll
        for (int b = 0; b < 8; ++b) {
            float p = ni[a] * na[b];
            const float* w = &sWsc[(a * 8 + b) * 16];
            #pragma unroll
            for (int c = 0; c < 16; ++c) sc[c] += p * w[c];
        }
    }

    float nf[16];
    #pragma unroll
    for (int c = 0; c < 16; ++c) {
        float t = 0.f;
        #pragma unroll
        for (int a = 0; a < 16; ++a) t += ni[a] * sW1[a * 16 + c];
        nf[c] = t;
    }
    float q[8];
    #pragma unroll
    for (int c = 0; c < 8; ++c) {
        float t = 0.f;
        #pragma unroll
        for (int a = 0; a < 16; ++a) t += nf[a] * sWq[a * 8 + c];
        q[c] = t;
    }
    float qk[8];
    #pragma unroll
    for (int c = 0; c < 8; ++c) {
        float t = 0.f;
        #pragma unroll
        for (int a = 0; a < 8; ++a) t += q[a] * sdot[a * 8 + c];
        qk[c] = t;
    }

    float4* nfo = (float4*)(nf_out + (size_t)n * 16);
    #pragma unroll
    for (int j = 0; j < 4; ++j) nfo[j] = make_float4(nf[4*j], nf[4*j+1], nf[4*j+2], nf[4*j+3]);
    float4* qko = (float4*)(qk_out + (size_t)n * 8);
    #pragma unroll
    for (int j = 0; j < 2; ++j) qko[j] = make_float4(qk[4*j], qk[4*j+1], qk[4*j+2], qk[4*j+3]);
    float4* sco = (float4*)(sc_out + (size_t)n * 16);
    #pragma unroll
    for (int j = 0; j < 4; ++j) sco[j] = make_float4(sc[4*j], sc[4*j+1], sc[4*j+2], sc[4*j+3]);
}

// ---------------- histogram ----------------
__global__ __launch_bounds__(256) void hist_kernel(
    const int* __restrict__ edge_dst, int* __restrict__ counts)
{
    int e = blockIdx.x * 256 + threadIdx.x;
    if (e < NE) atomicAdd(&counts[edge_dst[e]], 1);
}

// ---------------- scan: exclusive prefix of counts -> offs ----------------
__global__ __launch_bounds__(1024) void scan_kernel(
    const int* __restrict__ counts, int* __restrict__ offs)
{
    __shared__ int part[1024];
    int t = threadIdx.x;
    int base = t * 20;
    int s = 0;
    #pragma unroll 4
    for (int i = 0; i < 20; ++i) {
        int idx = base + i;
        if (idx < NN) s += counts[idx];
    }
    part[t] = s;
    __syncthreads();
    #pragma unroll
    for (int d = 1; d < 1024; d <<= 1) {
        int v = (t >= d) ? part[t - d] : 0;
        __syncthreads();
        part[t] += v;
        __syncthreads();
    }
    int run = part[t] - s;
    for (int i = 0; i < 20; ++i) {
        int idx = base + i;
        if (idx < NN) {
            offs[idx] = run;
            run += counts[idx];
        }
    }
}

// ---------------- placement: offs[dst]++ assigns slots; offs becomes inclusive ----------------
__global__ __launch_bounds__(256) void place_kernel(
    const int* __restrict__ edge_dst, int* __restrict__ offs, int* __restrict__ eids)
{
    int e = blockIdx.x * 256 + threadIdx.x;
    if (e >= NE) return;
    int dst = edge_dst[e];
    int pos = atomicAdd(&offs[dst], 1);
    eids[pos] = e;
}

// ---------------- MLP hiddens with transposed weights ----------------
__device__ __forceinline__ void mlp_hidden_t(const float es[16], const float* __restrict__ w0t,
                                             const float* __restrict__ w1t, const float* __restrict__ w2t,
                                             float out[8])
{
    float h0[8];
    #pragma unroll
    for (int j = 0; j < 8; ++j) {
        float t = 0.f;
        #pragma unroll
        for (int i = 0; i < 16; ++i) t += es[i] * w0t[j * 16 + i];
        h0[j] = silu_f(t);
    }
    float h1[8];
    #pragma unroll
    for (int j = 0; j < 8; ++j) {
        float t = 0.f;
        #pragma unroll
        for (int i = 0; i < 8; ++i) t += h0[i] * w1t[j * 8 + i];
        h1[j] = silu_f(t);
    }
    #pragma unroll
    for (int j = 0; j < 8; ++j) {
        float t = 0.f;
        #pragma unroll
        for (int i = 0; i < 8; ++i) t += h1[i] * w2t[j * 8 + i];
        out[j] = silu_f(t);
    }
}

// ---------------- edge kernel (CSR-sorted): hk, ea, src, v per slot ----------------
__global__ __launch_bounds__(256) void edge_kernel(
    const int* __restrict__ eids,
    const float* __restrict__ nf,
    const int* __restrict__ edge_src,
    const float* __restrict__ edge_attr, const float* __restrict__ edge_scalars,
    const float* __restrict__ fck_w0, const float* __restrict__ fck_w1,
    const float* __restrict__ fck_w2,
    const float* __restrict__ fcv_w0, const float* __restrict__ fcv_w1,
    const float* __restrict__ fcv_w2, const float* __restrict__ fcv_w3,
    float* __restrict__ hks, float* __restrict__ eas,
    int* __restrict__ srcs, float* __restrict__ vs)
{
    __shared__ float sk0t[128], sk1t[64], sk2t[64];
    __shared__ float sv0t[128], sv1t[64], sv2t[64], sv3t[512];
    int tid = threadIdx.x;
    for (int i = tid; i < 128; i += 256) { int r = i >> 3, c = i & 7; sk0t[c*16+r] = fck_w0[i] * 0.25f; }
    for (int i = tid; i < 64;  i += 256) { int r = i >> 3, c = i & 7; sk1t[c*8+r]  = fck_w1[i] * RS8; }
    for (int i = tid; i < 64;  i += 256) { int r = i >> 3, c = i & 7; sk2t[c*8+r]  = fck_w2[i] * RS8; }
    for (int i = tid; i < 128; i += 256) { int r = i >> 3, c = i & 7; sv0t[c*16+r] = fcv_w0[i] * 0.25f; }
    for (int i = tid; i < 64;  i += 256) { int r = i >> 3, c = i & 7; sv1t[c*8+r]  = fcv_w1[i] * RS8; }
    for (int i = tid; i < 64;  i += 256) { int r = i >> 3, c = i & 7; sv2t[c*8+r]  = fcv_w2[i] * RS8; }
    for (int i = tid; i < 512; i += 256) {
        int h = i >> 6, u = (i >> 2) & 15, w = i & 3;
        sv3t[u * 32 + h * 4 + w] = fcv_w3[i] * (RS8 * 0.5f);  // * 1/sqrt(4)
    }
    __syncthreads();

    int i = blockIdx.x * 256 + tid;
    if (i >= NE) return;
    int e = eids[i];

    float es[16];
    {
        const float4* p = (const float4*)(edge_scalars + (size_t)e * 16);
        #pragma unroll
        for (int j = 0; j < 4; ++j) {
            float4 t = p[j];
            es[4*j+0]=t.x; es[4*j+1]=t.y; es[4*j+2]=t.z; es[4*j+3]=t.w;
        }
    }

    float hk[8], hv[8];
    mlp_hidden_t(es, sk0t, sk1t, sk2t, hk);
    mlp_hidden_t(es, sv0t, sv1t, sv2t, hv);

    int src = edge_src[e];
    float sf[16];
    {
        const float4* p = (const float4*)(nf + (size_t)src * 16);
        #pragma unroll
        for (int j = 0; j < 4; ++j) {
            float4 t = p[j];
            sf[4*j+0]=t.x; sf[4*j+1]=t.y; sf[4*j+2]=t.z; sf[4*j+3]=t.w;
        }
    }
    float ea[4];
    {
        float4 t = *(const float4*)(edge_attr + (size_t)e * 4);
        ea[0]=t.x; ea[1]=t.y; ea[2]=t.z; ea[3]=t.w;
    }

    // v[u] = sf[u] * sum_{h,w} hv[h]*ea[w]*sv3t[u*32+h*4+w]
    float hw[32];
    #pragma unroll
    for (int h = 0; h < 8; ++h)
        #pragma unroll
        for (int w = 0; w < 4; ++w) hw[h*4+w] = hv[h] * ea[w];
    float vv[16];
    #pragma unroll
    for (int u = 0; u < 16; ++u) {
        float t = 0.f;
        const float* wp = &sv3t[u * 32];
        #pragma unroll
        for (int j = 0; j < 32; ++j) t += hw[j] * wp[j];
        vv[u] = sf[u] * t;
    }

    // sorted-slot stores (coalesced-ish, sequential rows)
    float4* hko = (float4*)(hks + (size_t)i * 8);
    hko[0] = make_float4(hk[0], hk[1], hk[2], hk[3]);
    hko[1] = make_float4(hk[4], hk[5], hk[6], hk[7]);
    *(float4*)(eas + (size_t)i * 4) = make_float4(ea[0], ea[1], ea[2], ea[3]);
    srcs[i] = src;
    float4* vo = (float4*)(vs + (size_t)i * 16);
    #pragma unroll
    for (int j = 0; j < 4; ++j) vo[j] = make_float4(vv[4*j], vv[4*j+1], vv[4*j+2], vv[4*j+3]);
}

// ---------------- gather + logits + softmax + output ----------------
// one wave per node; lane L owns R[h=L>>3][u=(L&7)*2+{0,1}][v=0..3] (8 values)
__global__ __launch_bounds__(256) void gather_out_kernel(
    const int* __restrict__ offs,
    const float* __restrict__ hks, const float* __restrict__ eas,
    const int* __restrict__ srcs, const float* __restrict__ vs,
    const float* __restrict__ nf, const float* __restrict__ qk,
    const float* __restrict__ fck_w3,
    const float* __restrict__ sc, const float* __restrict__ W_lin2,
    float* __restrict__ out)
{
    __shared__ float sW3[4096];   // [h][u*32+v*8+c], scale folded
    __shared__ float sW2[256];
    for (int i = threadIdx.x; i < 4096; i += 256) sW3[i] = fck_w3[i] * (RS8 * 0.125f);
    if (threadIdx.x < 256) sW2[threadIdx.x] = W_lin2[threadIdx.x] * 0.25f;
    __syncthreads();

    int wave = threadIdx.x >> 6;
    int L = threadIdx.x & 63;
    int n = blockIdx.x * 4 + wave;   // NN = 5000*4, all full

    int start = (n == 0) ? 0 : offs[n - 1];
    int end = offs[n];

    // per-node R fragment: R[j] = sum_c W3[h][u*32+v*8+c] * qk[n][c]
    float4 qk0, qk1;
    {
        const float4* p = (const float4*)(qk + (size_t)n * 8);
        qk0 = p[0]; qk1 = p[1];
    }
    int h = L >> 3;
    int u0 = (L & 7) * 2;
    float R[8];
    #pragma unroll
    for (int j = 0; j < 8; ++j) {
        int u = u0 + (j >> 2);
        int v = j & 3;
        const float* w = &sW3[h * 512 + u * 32 + v * 8];
        R[j] = w[0]*qk0.x + w[1]*qk0.y + w[2]*qk0.z + w[3]*qk0.w
             + w[4]*qk1.x + w[5]*qk1.y + w[6]*qk1.z + w[7]*qk1.w;
    }

    float accv = 0.f, accz = 0.f;
    for (int i = start; i < end; ++i) {
        float hkl = hks[(size_t)i * 8 + h];
        float4 ea = *(const float4*)(eas + (size_t)i * 4);
        int src = srcs[i];
        float2 sfp = *(const float2*)(nf + (size_t)src * 16 + u0);
        float d0 = R[0]*ea.x + R[1]*ea.y + R[2]*ea.z + R[3]*ea.w;
        float d1 = R[4]*ea.x + R[5]*ea.y + R[6]*ea.z + R[7]*ea.w;
        float px = hkl * (sfp.x * d0 + sfp.y * d1);
        #pragma unroll
        for (int s = 1; s < 64; s <<= 1) px += __shfl_xor(px, s);
        float exv = __expf(px);
        accz += exv;
        accv += exv * vs[(size_t)i * 16 + (L & 15)];
    }

    float den = (accz == 0.f) ? 1.f : accz;
    float a = accv / den;   // lanes 0..15 hold a[u=L]

    if (L < 16) {
        int c = L;
        float t = sc[(size_t)n * 16 + c];
        #pragma unroll
        for (int uu = 0; uu < 16; ++uu) {
            float au = __shfl(a, uu);
            t += au * sW2[uu * 16 + c];
        }
        out[(size_t)n * 16 + c] = t;
    }
}

} // namespace

extern "C" void kernel_launch(void* const* d_in, const int* in_sizes, int n_in,
                              void* d_out, int out_size, void* d_ws, size_t ws_size,
                              hipStream_t stream)
{
    const float* node_input   = (const float*)d_in[0];
    const float* node_attr    = (const float*)d_in[1];
    const int*   edge_src     = (const int*)d_in[2];
    const int*   edge_dst     = (const int*)d_in[3];
    const float* edge_attr    = (const float*)d_in[4];
    const float* edge_scalars = (const float*)d_in[5];
    const float* W_sc   = (const float*)d_in[6];
    const float* W_lin1 = (const float*)d_in[7];
    const float* W_hq   = (const float*)d_in[8];
    const float* fck_w0 = (const float*)d_in[9];
    const float* fck_w1 = (const float*)d_in[10];
    const float* fck_w2 = (const float*)d_in[11];
    const float* fck_w3 = (const float*)d_in[12];
    const float* fcv_w0 = (const float*)d_in[13];
    const float* fcv_w1 = (const float*)d_in[14];
    const float* fcv_w2 = (const float*)d_in[15];
    const float* fcv_w3 = (const float*)d_in[16];
    const float* W_dot  = (const float*)d_in[17];
    const float* W_lin2 = (const float*)d_in[18];

    float* ws  = (float*)d_ws;
    float* nf  = ws;                       // NN*16
    float* qk  = nf  + (size_t)NN * 16;    // NN*8
    float* sc  = qk  + (size_t)NN * 8;     // NN*16
    float* hks = sc  + (size_t)NN * 16;    // NE*8
    float* eas = hks + (size_t)NE * 8;     // NE*4
    float* vs  = eas + (size_t)NE * 4;     // NE*16
    int* srcs   = (int*)(vs + (size_t)NE * 16);  // NE
    int* counts = srcs + NE;                     // NN
    int* offs   = counts + NN;                   // NN
    int* eids   = offs + NN;                     // NE

    hipMemsetAsync(counts, 0, (size_t)NN * sizeof(int), stream);

    node_kernel<<<(NN + 255) / 256, 256, 0, stream>>>(
        node_input, node_attr, W_sc, W_lin1, W_hq, W_dot, nf, qk, sc);
    hist_kernel<<<(NE + 255) / 256, 256, 0, stream>>>(edge_dst, counts);
    scan_kernel<<<1, 1024, 0, stream>>>(counts, offs);
    place_kernel<<<(NE + 255) / 256, 256, 0, stream>>>(edge_dst, offs, eids);
    edge_kernel<<<(NE + 255) / 256, 256, 0, stream>>>(
        eids, nf, edge_src, edge_attr, edge_scalars,
        fck_w0, fck_w1, fck_w2, fcv_w0, fcv_w1, fcv_w2, fcv_w3,
        hks, eas, srcs, vs);
    gather_out_kernel<<<NN / 4, 256, 0, stream>>>(
        offs, hks, eas, srcs, vs, nf, qk, fck_w3, sc, W_lin2, (float*)d_out);
}

// Round 4
// 220.996 us; speedup vs baseline: 1.4700x; 1.4700x over previous
//
#include <hip/hip_runtime.h>
#include <math.h>

namespace {

constexpr int NN = 20000;   // nodes
constexpr int NE = 400000;  // edges

constexpr float RS8   = 0.35355339059327373f;  // 1/sqrt(8)
constexpr float RS128 = 0.08838834764831845f;  // 1/sqrt(128)

__device__ __forceinline__ float silu_f(float x) {
    return x / (1.0f + __expf(-x));
}

// ---------------- node kernel: sc, nf, qk ----------------
__global__ __launch_bounds__(256) void node_kernel(
    const float* __restrict__ node_input, const float* __restrict__ node_attr,
    const float* __restrict__ W_sc, const float* __restrict__ W_lin1,
    const float* __restrict__ W_hq, const float* __restrict__ W_dot,
    float* __restrict__ nf_out, float* __restrict__ qk_out, float* __restrict__ sc_out)
{
    __shared__ float sWsc[2048];   // [a][b][c] (16,8,16), scale folded
    __shared__ float sW1[256];     // [a][c] (16,16)
    __shared__ float sWq[128];     // [a][c] (16,8)
    __shared__ float sdot[64];     // [a][c] (8,8)
    for (int i = threadIdx.x; i < 2048; i += 256) sWsc[i] = W_sc[i] * RS128;
    if (threadIdx.x < 256) sW1[threadIdx.x] = W_lin1[threadIdx.x] * 0.25f;
    if (threadIdx.x < 128) sWq[threadIdx.x] = W_hq[threadIdx.x] * 0.25f;
    if (threadIdx.x < 64)  sdot[threadIdx.x] = W_dot[threadIdx.x] * 0.125f;  // 1/sqrt(64)
    __syncthreads();

    int n = blockIdx.x * 256 + threadIdx.x;
    if (n >= NN) return;

    float ni[16], na[8];
    {
        const float4* p = (const float4*)(node_input + (size_t)n * 16);
        #pragma unroll
        for (int j = 0; j < 4; ++j) {
            float4 t = p[j];
            ni[4*j+0]=t.x; ni[4*j+1]=t.y; ni[4*j+2]=t.z; ni[4*j+3]=t.w;
        }
        const float4* pa = (const float4*)(node_attr + (size_t)n * 8);
        #pragma unroll
        for (int j = 0; j < 2; ++j) {
            float4 t = pa[j];
            na[4*j+0]=t.x; na[4*j+1]=t.y; na[4*j+2]=t.z; na[4*j+3]=t.w;
        }
    }

    float sc[16];
    #pragma unroll
    for (int c = 0; c < 16; ++c) sc[c] = 0.f;
    #pragma unroll 4
    for (int a = 0; a < 16; ++a) {
        #pragma unroll
        for (int b = 0; b < 8; ++b) {
            float p = ni[a] * na[b];
            const float* w = &sWsc[(a * 8 + b) * 16];
            #pragma unroll
            for (int c = 0; c < 16; ++c) sc[c] += p * w[c];
        }
    }

    float nf[16];
    #pragma unroll
    for (int c = 0; c < 16; ++c) {
        float t = 0.f;
        #pragma unroll
        for (int a = 0; a < 16; ++a) t += ni[a] * sW1[a * 16 + c];
        nf[c] = t;
    }
    float q[8];
    #pragma unroll
    for (int c = 0; c < 8; ++c) {
        float t = 0.f;
        #pragma unroll
        for (int a = 0; a < 16; ++a) t += nf[a] * sWq[a * 8 + c];
        q[c] = t;
    }
    float qk[8];
    #pragma unroll
    for (int c = 0; c < 8; ++c) {
        float t = 0.f;
        #pragma unroll
        for (int a = 0; a < 8; ++a) t += q[a] * sdot[a * 8 + c];
        qk[c] = t;
    }

    float4* nfo = (float4*)(nf_out + (size_t)n * 16);
    #pragma unroll
    for (int j = 0; j < 4; ++j) nfo[j] = make_float4(nf[4*j], nf[4*j+1], nf[4*j+2], nf[4*j+3]);
    float4* qko = (float4*)(qk_out + (size_t)n * 8);
    #pragma unroll
    for (int j = 0; j < 2; ++j) qko[j] = make_float4(qk[4*j], qk[4*j+1], qk[4*j+2], qk[4*j+3]);
    float4* sco = (float4*)(sc_out + (size_t)n * 16);
    #pragma unroll
    for (int j = 0; j < 4; ++j) sco[j] = make_float4(sc[4*j], sc[4*j+1], sc[4*j+2], sc[4*j+3]);
}

// ---------------- histogram ----------------
__global__ __launch_bounds__(256) void hist_kernel(
    const int* __restrict__ edge_dst, int* __restrict__ counts)
{
    int e = blockIdx.x * 256 + threadIdx.x;
    if (e < NE) atomicAdd(&counts[edge_dst[e]], 1);
}

// ---------------- scan: exclusive prefix of counts -> offs ----------------
__global__ __launch_bounds__(1024) void scan_kernel(
    const int* __restrict__ counts, int* __restrict__ offs)
{
    __shared__ int part[1024];
    int t = threadIdx.x;
    int base = t * 20;
    int s = 0;
    #pragma unroll 4
    for (int i = 0; i < 20; ++i) {
        int idx = base + i;
        if (idx < NN) s += counts[idx];
    }
    part[t] = s;
    __syncthreads();
    #pragma unroll
    for (int d = 1; d < 1024; d <<= 1) {
        int v = (t >= d) ? part[t - d] : 0;
        __syncthreads();
        part[t] += v;
        __syncthreads();
    }
    int run = part[t] - s;
    for (int i = 0; i < 20; ++i) {
        int idx = base + i;
        if (idx < NN) {
            offs[idx] = run;
            run += counts[idx];
        }
    }
}

// ---------------- placement: offs[dst]++ assigns slots; offs becomes inclusive ----------------
__global__ __launch_bounds__(256) void place_kernel(
    const int* __restrict__ edge_dst, int* __restrict__ offs, int* __restrict__ eids)
{
    int e = blockIdx.x * 256 + threadIdx.x;
    if (e >= NE) return;
    int dst = edge_dst[e];
    int pos = atomicAdd(&offs[dst], 1);
    eids[pos] = e;
}

// ---------------- MLP hiddens with transposed weights ----------------
__device__ __forceinline__ void mlp_hidden_t(const float es[16], const float* __restrict__ w0t,
                                             const float* __restrict__ w1t, const float* __restrict__ w2t,
                                             float out[8])
{
    float h0[8];
    #pragma unroll
    for (int j = 0; j < 8; ++j) {
        float t = 0.f;
        #pragma unroll
        for (int i = 0; i < 16; ++i) t += es[i] * w0t[j * 16 + i];
        h0[j] = silu_f(t);
    }
    float h1[8];
    #pragma unroll
    for (int j = 0; j < 8; ++j) {
        float t = 0.f;
        #pragma unroll
        for (int i = 0; i < 8; ++i) t += h0[i] * w1t[j * 8 + i];
        h1[j] = silu_f(t);
    }
    #pragma unroll
    for (int j = 0; j < 8; ++j) {
        float t = 0.f;
        #pragma unroll
        for (int i = 0; i < 8; ++i) t += h1[i] * w2t[j * 8 + i];
        out[j] = silu_f(t);
    }
}

// ---------------- edge kernel (CSR-sorted): hk, ea, src, v per slot ----------------
__global__ __launch_bounds__(256) void edge_kernel(
    const int* __restrict__ eids,
    const float* __restrict__ nf,
    const int* __restrict__ edge_src,
    const float* __restrict__ edge_attr, const float* __restrict__ edge_scalars,
    const float* __restrict__ fck_w0, const float* __restrict__ fck_w1,
    const float* __restrict__ fck_w2,
    const float* __restrict__ fcv_w0, const float* __restrict__ fcv_w1,
    const float* __restrict__ fcv_w2, const float* __restrict__ fcv_w3,
    float* __restrict__ hks, float* __restrict__ eas,
    int* __restrict__ srcs, float* __restrict__ vs)
{
    __shared__ float sk0t[128], sk1t[64], sk2t[64];
    __shared__ float sv0t[128], sv1t[64], sv2t[64], sv3t[512];
    int tid = threadIdx.x;
    for (int i = tid; i < 128; i += 256) { int r = i >> 3, c = i & 7; sk0t[c*16+r] = fck_w0[i] * 0.25f; }
    for (int i = tid; i < 64;  i += 256) { int r = i >> 3, c = i & 7; sk1t[c*8+r]  = fck_w1[i] * RS8; }
    for (int i = tid; i < 64;  i += 256) { int r = i >> 3, c = i & 7; sk2t[c*8+r]  = fck_w2[i] * RS8; }
    for (int i = tid; i < 128; i += 256) { int r = i >> 3, c = i & 7; sv0t[c*16+r] = fcv_w0[i] * 0.25f; }
    for (int i = tid; i < 64;  i += 256) { int r = i >> 3, c = i & 7; sv1t[c*8+r]  = fcv_w1[i] * RS8; }
    for (int i = tid; i < 64;  i += 256) { int r = i >> 3, c = i & 7; sv2t[c*8+r]  = fcv_w2[i] * RS8; }
    for (int i = tid; i < 512; i += 256) {
        int h = i >> 6, u = (i >> 2) & 15, w = i & 3;
        sv3t[u * 32 + h * 4 + w] = fcv_w3[i] * (RS8 * 0.5f);  // * 1/sqrt(4)
    }
    __syncthreads();

    int i = blockIdx.x * 256 + tid;
    if (i >= NE) return;
    int e = eids[i];

    float es[16];
    {
        const float4* p = (const float4*)(edge_scalars + (size_t)e * 16);
        #pragma unroll
        for (int j = 0; j < 4; ++j) {
            float4 t = p[j];
            es[4*j+0]=t.x; es[4*j+1]=t.y; es[4*j+2]=t.z; es[4*j+3]=t.w;
        }
    }

    float hk[8], hv[8];
    mlp_hidden_t(es, sk0t, sk1t, sk2t, hk);
    mlp_hidden_t(es, sv0t, sv1t, sv2t, hv);

    int src = edge_src[e];
    float sf[16];
    {
        const float4* p = (const float4*)(nf + (size_t)src * 16);
        #pragma unroll
        for (int j = 0; j < 4; ++j) {
            float4 t = p[j];
            sf[4*j+0]=t.x; sf[4*j+1]=t.y; sf[4*j+2]=t.z; sf[4*j+3]=t.w;
        }
    }
    float ea[4];
    {
        float4 t = *(const float4*)(edge_attr + (size_t)e * 4);
        ea[0]=t.x; ea[1]=t.y; ea[2]=t.z; ea[3]=t.w;
    }

    // v[u] = sf[u] * sum_{h,w} hv[h]*ea[w]*sv3t[u*32+h*4+w]
    float hw[32];
    #pragma unroll
    for (int h = 0; h < 8; ++h)
        #pragma unroll
        for (int w = 0; w < 4; ++w) hw[h*4+w] = hv[h] * ea[w];
    float vv[16];
    #pragma unroll
    for (int u = 0; u < 16; ++u) {
        float t = 0.f;
        const float* wp = &sv3t[u * 32];
        #pragma unroll
        for (int j = 0; j < 32; ++j) t += hw[j] * wp[j];
        vv[u] = sf[u] * t;
    }

    // sorted-slot stores
    float4* hko = (float4*)(hks + (size_t)i * 8);
    hko[0] = make_float4(hk[0], hk[1], hk[2], hk[3]);
    hko[1] = make_float4(hk[4], hk[5], hk[6], hk[7]);
    *(float4*)(eas + (size_t)i * 4) = make_float4(ea[0], ea[1], ea[2], ea[3]);
    srcs[i] = src;
    float4* vo = (float4*)(vs + (size_t)i * 16);
    #pragma unroll
    for (int j = 0; j < 4; ++j) vo[j] = make_float4(vv[4*j], vv[4*j+1], vv[4*j+2], vv[4*j+3]);
}

// ---------------- gather + logits + softmax + output ----------------
// one wave per node. lane L = (g = L>>4, u = L&15); lane owns
// R[h][u][v] for h in {2g, 2g+1}, v=0..3 (8 floats, unique across the wave).
// 4 edges per iteration, interleaved 6-step butterflies; group g accumulates edge i0+g.
__global__ __launch_bounds__(256) void gather_out_kernel(
    const int* __restrict__ offs,
    const float* __restrict__ hks, const float* __restrict__ eas,
    const int* __restrict__ srcs, const float* __restrict__ vs,
    const float* __restrict__ nf, const float* __restrict__ qk,
    const float* __restrict__ fck_w3,
    const float* __restrict__ sc, const float* __restrict__ W_lin2,
    float* __restrict__ out)
{
    int wave = threadIdx.x >> 6;
    int L = threadIdx.x & 63;
    int n = blockIdx.x * 4 + wave;   // NN = 5000*4, all full
    int g = L >> 4;
    int u = L & 15;

    int start = (n == 0) ? 0 : offs[n - 1];
    int end = offs[n];

    // qk for this node (8 floats, broadcast load within wave)
    float qkv[8];
    {
        const float4* p = (const float4*)(qk + (size_t)n * 8);
        float4 a = p[0], b = p[1];
        qkv[0]=a.x; qkv[1]=a.y; qkv[2]=a.z; qkv[3]=a.w;
        qkv[4]=b.x; qkv[5]=b.y; qkv[6]=b.z; qkv[7]=b.w;
    }

    // R fragment from global fck_w3 (16 KB, L1-resident): Rf[dh*4+v]
    constexpr float S3 = RS8 * 0.125f;
    float Rf[8];
    #pragma unroll
    for (int dh = 0; dh < 2; ++dh) {
        int h = 2 * g + dh;
        #pragma unroll
        for (int v = 0; v < 4; ++v) {
            const float4* w = (const float4*)(fck_w3 + h * 512 + u * 32 + v * 8);
            float4 w0 = w[0], w1 = w[1];
            float t = w0.x*qkv[0] + w0.y*qkv[1] + w0.z*qkv[2] + w0.w*qkv[3]
                    + w1.x*qkv[4] + w1.y*qkv[5] + w1.z*qkv[6] + w1.w*qkv[7];
            Rf[dh * 4 + v] = t * S3;
        }
    }

    float accv = 0.f, accz = 0.f;
    for (int i0 = start; i0 < end; i0 += 4) {
        float px[4];
        #pragma unroll
        for (int e = 0; e < 4; ++e) {
            int ii = i0 + e;
            int ic = (ii < end) ? ii : (end - 1);   // clamp loads, mask at use
            float2 hk2 = *(const float2*)(hks + (size_t)ic * 8 + 2 * g);
            float4 ea = *(const float4*)(eas + (size_t)ic * 4);
            int src = srcs[ic];
            float sfu = nf[(size_t)src * 16 + u];
            float d0 = ea.x*Rf[0] + ea.y*Rf[1] + ea.z*Rf[2] + ea.w*Rf[3];
            float d1 = ea.x*Rf[4] + ea.y*Rf[5] + ea.z*Rf[6] + ea.w*Rf[7];
            px[e] = sfu * (hk2.x * d0 + hk2.y * d1);
        }
        // 4 interleaved 64-lane butterflies
        #pragma unroll
        for (int s = 1; s < 64; s <<= 1) {
            px[0] += __shfl_xor(px[0], s);
            px[1] += __shfl_xor(px[1], s);
            px[2] += __shfl_xor(px[2], s);
            px[3] += __shfl_xor(px[3], s);
        }
        // group g takes edge i0+g
        int ig = i0 + g;
        if (ig < end) {
            float xg = (g == 0) ? px[0] : (g == 1) ? px[1] : (g == 2) ? px[2] : px[3];
            float exv = __expf(xg);
            accz += exv;                                // identical across the 16 lanes of g
            accv += exv * vs[(size_t)ig * 16 + u];
        }
    }

    // cross-group reduction (groups handled disjoint edges)
    accv += __shfl_xor(accv, 16);
    accv += __shfl_xor(accv, 32);
    accz += __shfl_xor(accz, 16);
    accz += __shfl_xor(accz, 32);

    float den = (accz == 0.f) ? 1.f : accz;
    float a = 0.25f * accv / den;    // fold W_lin2's 1/sqrt(16) here

    if (L < 16) {
        int c = L;
        float t = sc[(size_t)n * 16 + c];
        #pragma unroll
        for (int uu = 0; uu < 16; ++uu) {
            float au = __shfl(a, uu);
            t += au * W_lin2[uu * 16 + c];   // 1 KB table, L1-resident
        }
        out[(size_t)n * 16 + c] = t;
    }
}

} // namespace

extern "C" void kernel_launch(void* const* d_in, const int* in_sizes, int n_in,
                              void* d_out, int out_size, void* d_ws, size_t ws_size,
                              hipStream_t stream)
{
    const float* node_input   = (const float*)d_in[0];
    const float* node_attr    = (const float*)d_in[1];
    const int*   edge_src     = (const int*)d_in[2];
    const int*   edge_dst     = (const int*)d_in[3];
    const float* edge_attr    = (const float*)d_in[4];
    const float* edge_scalars = (const float*)d_in[5];
    const float* W_sc   = (const float*)d_in[6];
    const float* W_lin1 = (const float*)d_in[7];
    const float* W_hq   = (const float*)d_in[8];
    const float* fck_w0 = (const float*)d_in[9];
    const float* fck_w1 = (const float*)d_in[10];
    const float* fck_w2 = (const float*)d_in[11];
    const float* fck_w3 = (const float*)d_in[12];
    const float* fcv_w0 = (const float*)d_in[13];
    const float* fcv_w1 = (const float*)d_in[14];
    const float* fcv_w2 = (const float*)d_in[15];
    const float* fcv_w3 = (const float*)d_in[16];
    const float* W_dot  = (const float*)d_in[17];
    const float* W_lin2 = (const float*)d_in[18];

    float* ws  = (float*)d_ws;
    float* nf  = ws;                       // NN*16
    float* qk  = nf  + (size_t)NN * 16;    // NN*8
    float* sc  = qk  + (size_t)NN * 8;     // NN*16
    float* hks = sc  + (size_t)NN * 16;    // NE*8
    float* eas = hks + (size_t)NE * 8;     // NE*4
    float* vs  = eas + (size_t)NE * 4;     // NE*16
    int* srcs   = (int*)(vs + (size_t)NE * 16);  // NE
    int* counts = srcs + NE;                     // NN
    int* offs   = counts + NN;                   // NN
    int* eids   = offs + NN;                     // NE

    hipMemsetAsync(counts, 0, (size_t)NN * sizeof(int), stream);

    node_kernel<<<(NN + 255) / 256, 256, 0, stream>>>(
        node_input, node_attr, W_sc, W_lin1, W_hq, W_dot, nf, qk, sc);
    hist_kernel<<<(NE + 255) / 256, 256, 0, stream>>>(edge_dst, counts);
    scan_kernel<<<1, 1024, 0, stream>>>(counts, offs);
    place_kernel<<<(NE + 255) / 256, 256, 0, stream>>>(edge_dst, offs, eids);
    edge_kernel<<<(NE + 255) / 256, 256, 0, stream>>>(
        eids, nf, edge_src, edge_attr, edge_scalars,
        fck_w0, fck_w1, fck_w2, fcv_w0, fcv_w1, fcv_w2, fcv_w3,
        hks, eas, srcs, vs);
    gather_out_kernel<<<NN / 4, 256, 0, stream>>>(
        offs, hks, eas, srcs, vs, nf, qk, fck_w3, sc, W_lin2, (float*)d_out);
}